// Round 1
// baseline (2667.717 us; speedup 1.0000x reference)
//
#include <hip/hip_runtime.h>
#include <hip/hip_bf16.h>

using bf16 = __hip_bfloat16;
typedef short short8 __attribute__((ext_vector_type(8)));
typedef float f32x4 __attribute__((ext_vector_type(4)));

#define NT 196416  // NUM_ANCHORS * sum(h*w)

// ---------------- prep kernels ----------------

__global__ void cast_feat_kernel(const float* __restrict__ in, bf16* __restrict__ out, int n) {
  for (int i = blockIdx.x * blockDim.x + threadIdx.x; i < n; i += gridDim.x * blockDim.x)
    out[i] = __float2bfloat16(in[i]);
}

// src [G][Ci][Co] f32  ->  dst [G][Co][Ci] bf16
__global__ void transpose_w_kernel(const float* __restrict__ src, bf16* __restrict__ dst,
                                   int G, int Ci, int Co) {
  int n = G * Ci * Co;
  for (int i = blockIdx.x * blockDim.x + threadIdx.x; i < n; i += gridDim.x * blockDim.x) {
    int g = i / (Ci * Co);
    int r = i - g * (Ci * Co);
    int co = r / Ci;
    int ci = r - co * Ci;
    dst[i] = __float2bfloat16(src[(g * Ci + ci) * Co + co]);
  }
}

// ---------------- conv implicit-GEMM ----------------
// in:  bf16 activations [B=2, H, W, 256] (NHWC)
// wt:  bf16 weights [TAPS][Cout][256]  (tap = ky*3+kx, dy=ky-1, dx=kx-1)
// out[m][co] = sum_t sum_ci in[shift(m,t)][ci] * wt[t][co][ci]   (+bias, relu)
// EPI: 0 = store bf16 activation, 1 = focal loss accumulate, 2 = L1 box loss accumulate
template <int TAPS, int EPI, bool RELU>
__global__ __launch_bounds__(256) void conv_gemm_kernel(
    const bf16* __restrict__ in, const bf16* __restrict__ wt,
    const float* __restrict__ bias, bf16* __restrict__ out,
    int H, int W, int Cout,
    const int* __restrict__ labels, const float* __restrict__ tdel,
    int abase, float* __restrict__ lout) {
  const int HW = H * W;
  const int Mtot = 2 * HW;
  const int m0 = blockIdx.x * 64;
  const int n0 = blockIdx.y * 64;
  const int tid = threadIdx.x;
  const int lane = tid & 63;
  const int wid = tid >> 6;
  const int wm = wid >> 1;      // wave row (0..1)
  const int wn = wid & 1;       // wave col (0..1)
  const int l15 = lane & 15;
  const int lk = (lane >> 4) * 8;  // k offset within 32-chunk

  __shared__ __align__(16) bf16 As[64][40];  // [pixel][ci]  (pad to 40 elems)
  __shared__ __align__(16) bf16 Bs[64][40];  // [cout][ci]
  __shared__ float red[4];

  // staging coords, fixed per thread
  const int sp = tid >> 2;          // slot 0..63
  const int sc = (tid & 3) * 8;     // ci offset 0/8/16/24
  const int gm = m0 + sp;
  const bool mval = gm < Mtot;
  int b = 0, h = 0, w = 0;
  if (mval) { b = gm / HW; int r = gm - b * HW; h = r / W; w = r - h * W; }
  const int co_g = n0 + sp;
  const bool nval = co_g < Cout;

  const f32x4 zero = {0.f, 0.f, 0.f, 0.f};
  f32x4 acc[2][2];
  acc[0][0] = zero; acc[0][1] = zero; acc[1][0] = zero; acc[1][1] = zero;

  for (int t = 0; t < TAPS; ++t) {
    int dy = 0, dx = 0;
    if (TAPS == 9) { dy = t / 3 - 1; dx = t - (t / 3) * 3 - 1; }
    const int hh = h + dy, ww = w + dx;
    const bool v = mval && ((unsigned)hh < (unsigned)H) && ((unsigned)ww < (unsigned)W);
    const bf16* src = in + (size_t)((b * HW + hh * W + ww)) * 256 + sc;
    const bf16* wsrc = wt + (size_t)(t * Cout + co_g) * 256 + sc;

    for (int c0 = 0; c0 < 256; c0 += 32) {
      short8 av = 0, bv = 0;
      if (v) av = *(const short8*)(src + c0);
      if (nval) bv = *(const short8*)(wsrc + c0);
      __syncthreads();  // previous iteration's fragment reads done
      *(short8*)&As[sp][sc] = av;
      *(short8*)&Bs[sp][sc] = bv;
      __syncthreads();
      short8 a0 = *(const short8*)&As[wm * 32 + l15][lk];
      short8 a1 = *(const short8*)&As[wm * 32 + 16 + l15][lk];
      short8 b0 = *(const short8*)&Bs[wn * 32 + l15][lk];
      short8 b1 = *(const short8*)&Bs[wn * 32 + 16 + l15][lk];
      acc[0][0] = __builtin_amdgcn_mfma_f32_16x16x32_bf16(a0, b0, acc[0][0], 0, 0, 0);
      acc[0][1] = __builtin_amdgcn_mfma_f32_16x16x32_bf16(a0, b1, acc[0][1], 0, 0, 0);
      acc[1][0] = __builtin_amdgcn_mfma_f32_16x16x32_bf16(a1, b0, acc[1][0], 0, 0, 0);
      acc[1][1] = __builtin_amdgcn_mfma_f32_16x16x32_bf16(a1, b1, acc[1][1], 0, 0, 0);
    }
  }

  const int rbase = (lane >> 4) * 2;  // not used; keep simple below
  (void)rbase;

  if constexpr (EPI == 0) {
#pragma unroll
    for (int mf = 0; mf < 2; ++mf)
#pragma unroll
      for (int nf = 0; nf < 2; ++nf) {
        const int n = n0 + wn * 32 + nf * 16 + l15;
        if (n < Cout) {
          const float bvv = bias[n];
#pragma unroll
          for (int r = 0; r < 4; ++r) {
            const int m = m0 + wm * 32 + mf * 16 + (lane >> 4) * 4 + r;
            if (m < Mtot) {
              float vv = acc[mf][nf][r] + bvv;
              if (RELU) vv = fmaxf(vv, 0.f);
              out[(size_t)m * Cout + n] = __float2bfloat16(vv);
            }
          }
        }
      }
  } else {
    float lsum = 0.f;
#pragma unroll
    for (int mf = 0; mf < 2; ++mf)
#pragma unroll
      for (int nf = 0; nf < 2; ++nf) {
        const int n = n0 + wn * 32 + nf * 16 + l15;
        if (n < Cout) {
          const float bvv = bias[n];
#pragma unroll
          for (int r = 0; r < 4; ++r) {
            const int m = m0 + wm * 32 + mf * 16 + (lane >> 4) * 4 + r;
            if (m < Mtot) {
              const float z = acc[mf][nf][r] + bvv;
              const int b2 = m / HW;
              const int rr = m - b2 * HW;  // h*W + w
              if constexpr (EPI == 1) {
                const int a = n / 80;
                const int k = n - a * 80;
                const int label = labels[b2 * NT + abase + rr * 9 + a];
                if (label >= 0) {
                  const float tt = (label == k) ? 1.f : 0.f;
                  const float ce = fmaxf(z, 0.f) - z * tt + log1pf(expf(-fabsf(z)));
                  const float p = 1.f / (1.f + expf(-z));
                  const float pt = p * tt + (1.f - p) * (1.f - tt);
                  const float om = 1.f - pt;
                  lsum += (0.25f * tt + 0.75f * (1.f - tt)) * ce * om * om;
                }
              } else {
                const int a = n >> 2;
                const int pi = n & 3;
                const int idx = abase + rr * 9 + a;
                const int label = labels[b2 * NT + idx];
                if (label >= 0 && label != 80) {
                  lsum += fabsf(z - tdel[((size_t)b2 * NT + idx) * 4 + pi]);
                }
              }
            }
          }
        }
      }
#pragma unroll
    for (int off = 32; off > 0; off >>= 1) lsum += __shfl_down(lsum, off);
    if ((tid & 63) == 0) red[tid >> 6] = lsum;
    __syncthreads();
    if (tid == 0) atomicAdd(lout, (red[0] + red[1] + red[2] + red[3]) * 0.01f);
  }
}

// ---------------- host ----------------

static inline int igrid(long long n, int cap) {
  long long g = (n + 255) / 256;
  if (g > cap) g = cap;
  return (int)g;
}

extern "C" void kernel_launch(void* const* d_in, const int* in_sizes, int n_in,
                              void* d_out, int out_size, void* d_ws, size_t ws_size,
                              hipStream_t stream) {
  const float* feat_in[5] = {(const float*)d_in[0], (const float*)d_in[1],
                             (const float*)d_in[2], (const float*)d_in[3],
                             (const float*)d_in[4]};
  const int* labels = (const int*)d_in[5];
  const float* adeltas = (const float*)d_in[6];
  const float* ipw = (const float*)d_in[7];
  const float* ipb = (const float*)d_in[8];
  const float* ccw = (const float*)d_in[9];
  const float* ccb = (const float*)d_in[10];
  const float* csw = (const float*)d_in[11];
  const float* csb = (const float*)d_in[12];
  const float* bcw = (const float*)d_in[13];
  const float* bcb = (const float*)d_in[14];
  const float* bpw = (const float*)d_in[15];
  const float* bpb = (const float*)d_in[16];
  float* out = (float*)d_out;

  // workspace layout (bf16 elems)
  bf16* feats = (bf16*)d_ws;                 // 11,173,888
  bf16* xbuf = feats + 11173888;             // 8,388,608
  bf16* t0 = xbuf + 8388608;                 // 8,388,608
  bf16* t1 = t0 + 8388608;                   // 8,388,608
  bf16* w_ip = t1 + 8388608;                 // 5*256*256   = 327,680
  bf16* w_cls = w_ip + 327680;               // 36*256*256  = 2,359,296
  bf16* w_box = w_cls + 2359296;             // 36*256*256
  bf16* w_score = w_box + 2359296;           // 9*720*256   = 1,658,880
  bf16* w_pred = w_score + 1658880;          // 9*36*256    = 82,944

  hipMemsetAsync(d_out, 0, 2 * sizeof(float), stream);

  static const int LH[5] = {128, 64, 32, 16, 8};
  static const int AB[5] = {0, 147456, 184320, 193536, 195840};

  // cast feats to bf16
  size_t foff[5];
  size_t off = 0;
  for (int l = 0; l < 5; ++l) {
    int n = 2 * LH[l] * LH[l] * 256;
    foff[l] = off;
    cast_feat_kernel<<<igrid(n, 4096), 256, 0, stream>>>(feat_in[l], feats + off, n);
    off += (size_t)n;
  }

  // transpose+cast weights -> [G][Co][Ci] bf16
  transpose_w_kernel<<<igrid(5LL * 256 * 256, 2048), 256, 0, stream>>>(ipw, w_ip, 5, 256, 256);
  transpose_w_kernel<<<igrid(36LL * 256 * 256, 4096), 256, 0, stream>>>(ccw, w_cls, 36, 256, 256);
  transpose_w_kernel<<<igrid(36LL * 256 * 256, 4096), 256, 0, stream>>>(bcw, w_box, 36, 256, 256);
  transpose_w_kernel<<<igrid(9LL * 256 * 720, 4096), 256, 0, stream>>>(csw, w_score, 9, 256, 720);
  transpose_w_kernel<<<igrid(9LL * 256 * 36, 2048), 256, 0, stream>>>(bpw, w_pred, 9, 256, 36);

  for (int l = 0; l < 5; ++l) {
    const int H = LH[l], W = LH[l];
    const int Mtot = 2 * H * W;
    const int mt = (Mtot + 63) / 64;
    // in_proj (1x1)
    conv_gemm_kernel<1, 0, false><<<dim3(mt, 4), 256, 0, stream>>>(
        feats + foff[l], w_ip + l * 65536, ipb + l * 256, xbuf, H, W, 256,
        nullptr, nullptr, 0, nullptr);
    // cls branch
    const bf16* cin = xbuf;
    bf16* pp[2] = {t0, t1};
    for (int j = 0; j < 4; ++j) {
      conv_gemm_kernel<9, 0, true><<<dim3(mt, 4), 256, 0, stream>>>(
          cin, w_cls + (size_t)j * 589824, ccb + j * 256, pp[j & 1], H, W, 256,
          nullptr, nullptr, 0, nullptr);
      cin = pp[j & 1];
    }
    conv_gemm_kernel<9, 1, false><<<dim3(mt, 12), 256, 0, stream>>>(
        cin, w_score, csb, nullptr, H, W, 720, labels, nullptr, AB[l], out + 0);
    // box branch
    cin = xbuf;
    for (int j = 0; j < 4; ++j) {
      conv_gemm_kernel<9, 0, true><<<dim3(mt, 4), 256, 0, stream>>>(
          cin, w_box + (size_t)j * 589824, bcb + j * 256, pp[j & 1], H, W, 256,
          nullptr, nullptr, 0, nullptr);
      cin = pp[j & 1];
    }
    conv_gemm_kernel<9, 2, false><<<dim3(mt, 1), 256, 0, stream>>>(
        cin, w_pred, bpb, nullptr, H, W, 36, labels, adeltas, AB[l], out + 1);
  }
}

// Round 2
// 1665.923 us; speedup vs baseline: 1.6013x; 1.6013x over previous
//
#include <hip/hip_runtime.h>
#include <hip/hip_bf16.h>

using bf16 = __hip_bfloat16;
typedef short short8 __attribute__((ext_vector_type(8)));
typedef short short4v __attribute__((ext_vector_type(4)));
typedef float f32x16 __attribute__((ext_vector_type(16)));

#define NT 196416

__device__ __forceinline__ void gload16(const void* g, void* l) {
  __builtin_amdgcn_global_load_lds((const __attribute__((address_space(1))) void*)g,
                                   (__attribute__((address_space(3))) void*)l, 16, 0, 0);
}

// ---------------- prep: weights HWIO -> staged slot order ----------------
// staged (per layer): [nb][k(8)][c(4)][tap][col(64)] of short8 (8 ci each)
// value[j] = w[tap][ci = k*32+c*8+j][co = nb*64+col]  (0 if co >= Cout)
__global__ void prep_w(const float* __restrict__ src, bf16* __restrict__ dst,
                       int Cout, int NB, int TP, int layers, long sstride) {
  const long spl = (long)NB * 8 * 4 * TP * 64;  // 16B slots per layer
  const long total = spl * layers;
  for (long t = blockIdx.x * (long)blockDim.x + threadIdx.x; t < total;
       t += (long)gridDim.x * blockDim.x) {
    long layer = t / spl;
    long r = t - layer * spl;
    int nb = (int)(r / (2048L * TP));
    int r2 = (int)(r - (long)nb * 2048 * TP);
    int k = r2 / (256 * TP);
    int r3 = r2 - k * 256 * TP;
    int c = r3 / (64 * TP);
    int r4 = r3 - c * 64 * TP;
    int tap = r4 >> 6;
    int col = r4 & 63;
    int co = nb * 64 + col;
    short8 v = {};
    if (co < Cout) {
      const float* s = src + layer * sstride + ((long)(tap * 256 + k * 32 + c * 8)) * Cout + co;
#pragma unroll
      for (int j = 0; j < 8; ++j) {
        union { bf16 b; short s16; } u;
        u.b = __float2bfloat16(s[(long)j * Cout]);
        v[j] = u.s16;
      }
    }
    *(short8*)(dst + t * 8) = v;
  }
}

// ---------------- halo zero (3 buffers at level shape) ----------------
__global__ void halo3_kernel(bf16* __restrict__ base, long bufstride, int H, int W) {
  const int P = 2 * (W + 2) + 2 * H;
  const long n = 3L * 2 * P * 256;
  for (long t = blockIdx.x * (long)blockDim.x + threadIdx.x; t < n;
       t += (long)gridDim.x * blockDim.x) {
    int ch = (int)(t & 255);
    long q = t >> 8;
    int pix = (int)(q % P);
    int q2 = (int)(q / P);
    int img = q2 & 1;
    int buf = q2 >> 1;
    int row, col;
    if (pix < W + 2) { row = 0; col = pix; }
    else if (pix < 2 * (W + 2)) { row = H + 1; col = pix - (W + 2); }
    else { int e = pix - 2 * (W + 2); row = 1 + (e >> 1); col = (e & 1) ? W + 1 : 0; }
    bf16* p = base + buf * bufstride + ((long)(img * (H + 2) + row) * (W + 2) + col) * 256 + ch;
    union { bf16 b; short s16; } u; u.s16 = 0;
    *p = u.b;
  }
}

// ---------------- cast feats (f32, unpadded) -> bf16 padded interior ----------------
__global__ void cast_feat_kernel(const float* __restrict__ in, bf16* __restrict__ out,
                                 int H, int wshift) {
  const int W = 1 << wshift;
  const long n4 = 2L * H * W * 64;
  for (long t = blockIdx.x * (long)blockDim.x + threadIdx.x; t < n4;
       t += (long)gridDim.x * blockDim.x) {
    int c4 = (int)(t & 63);
    long q = t >> 6;
    int w = (int)(q & (W - 1));
    long q2 = q >> wshift;
    int h = (int)(q2 & (H - 1));
    int b = (int)(q2 >> wshift);
    const float4 f = *(const float4*)(in + (((long)(b * H + h) * W + w) * 256 + c4 * 4));
    short4v v;
    union { bf16 b16; short s16; } u;
    u.b16 = __float2bfloat16(f.x); v[0] = u.s16;
    u.b16 = __float2bfloat16(f.y); v[1] = u.s16;
    u.b16 = __float2bfloat16(f.z); v[2] = u.s16;
    u.b16 = __float2bfloat16(f.w); v[3] = u.s16;
    *(short4v*)(out + (((long)(b * (H + 2) + h + 1) * (W + 2) + w + 1) * 256 + c4 * 4)) = v;
  }
}

// ---------------- conv implicit GEMM, spatial-patch, 32x32x16 MFMA ----------------
// in  : padded bf16 activations [2][H+2][W+2][256]
// wp  : prepped weights [NB][8][4*TAPS*64 slots]
// EPI : 0 store relu/linear activation into padded out; 1 focal loss; 2 L1 box loss
template <int BM, int WM, int WN, int TAPS, int EPI, int PM>
__global__ __launch_bounds__(WM * WN * 64, 4) void conv_t(
    const bf16* __restrict__ in, const bf16* __restrict__ wp,
    const float* __restrict__ bias, bf16* __restrict__ outp,
    int H, int wshift, const int* __restrict__ labels,
    const float* __restrict__ tdel, int abase, float* __restrict__ lout, int Cout) {
  constexpr int BLOCK = WM * WN * 64;
  constexpr int MF = BM / WM / 32;
  constexpr int NROW = TAPS * 64;          // B rows per ci-group
  constexpr int BOFF = 64 * PM;            // byte offset of B region in LDS
  constexpr int NB_SLOTS = TAPS * 256;     // B 16B-slots per chunk
  constexpr int CG = BLOCK / 4;            // threads per ci-group for A staging

  __shared__ char smem[64 * PM + TAPS * 4096];

  const int W = 1 << wshift;
  const int tid = threadIdx.x;
  const int lane = tid & 63;
  const int wid = tid >> 6;
  const int wm = wid / WN;
  const int wn = wid % WN;
  const int lh = lane >> 5;   // 0/1
  const int l31 = lane & 31;

  const int R = BM >> wshift;
  const int PP = (R + 2) * (W + 2);
  const int img = blockIdx.z;
  const int rb = blockIdx.x;
  const int n0 = blockIdx.y * 64;
  const int W2_16 = (W + 2) * 16;

  // A fragment LDS byte bases (ks=0 ci-group; ks=1 adds PP*32)
  int aOff[MF];
#pragma unroll
  for (int mf = 0; mf < MF; ++mf) {
    const int mrow = wm * (BM / WM) + mf * 32 + l31;
    const int pb = (mrow >> wshift) * (W + 2) + (mrow & (W - 1));
    aOff[mf] = (lh * PP + pb) * 16;
  }
  const int bOff = (lh * NROW + wn * 32 + l31) * 16;

  // staging constants
  const int cst = tid / CG;
  const int lig = tid - cst * CG;
  const int wib = tid & ~63;
  const int ldsA_base = (cst * PP + (wib % CG)) * 16;  // wave-uniform
  const bf16* gA = in + ((long)(img * (H + 2) + rb * R) * (W + 2)) * 256 + cst * 8;
  const bf16* gB = wp + ((long)blockIdx.y * TAPS * 2048 + tid) * 8;
  const int nkk = (PP + CG - 1) / CG;

  f32x16 acc[MF];
#pragma unroll
  for (int mf = 0; mf < MF; ++mf) acc[mf] = (f32x16)(0.f);

  for (int k = 0; k < 8; ++k) {
    __syncthreads();
    // stage A patch chunk (32 ci): layout [c(4)][pixel]
    for (int kk = 0; kk < nkk; ++kk) {
      const int p = kk * CG + lig;
      if (p < PP)
        gload16(gA + (long)p * 256 + k * 32, smem + ldsA_base + kk * CG * 16);
    }
    // stage B chunk (prepped, slot-linear)
#pragma unroll
    for (int s0 = 0; s0 < NB_SLOTS; s0 += BLOCK) {
      if (s0 + tid < NB_SLOTS)
        gload16(gB + ((long)k * NB_SLOTS + s0) * 8, smem + BOFF + (s0 + wib) * 16);
    }
    __syncthreads();
    // compute: taps x (MF x 2 k-slices)
#pragma unroll
    for (int t = 0; t < TAPS; ++t) {
      int toff;
      if (TAPS == 9) toff = (t / 3) * W2_16 + (t % 3) * 16;
      else toff = W2_16 + 16;
      const short8 b0 = *(const short8*)(smem + BOFF + bOff + t * 1024);
      const short8 b1 = *(const short8*)(smem + BOFF + bOff + NROW * 32 + t * 1024);
#pragma unroll
      for (int mf = 0; mf < MF; ++mf) {
        const short8 a0 = *(const short8*)(smem + aOff[mf] + toff);
        const short8 a1 = *(const short8*)(smem + aOff[mf] + PP * 32 + toff);
        acc[mf] = __builtin_amdgcn_mfma_f32_32x32x16_bf16(a0, b0, acc[mf], 0, 0, 0);
        acc[mf] = __builtin_amdgcn_mfma_f32_32x32x16_bf16(a1, b1, acc[mf], 0, 0, 0);
      }
    }
  }

  const int co = n0 + wn * 32 + l31;

  if constexpr (EPI == 0) {
    const float bv = bias[co];
#pragma unroll
    for (int mf = 0; mf < MF; ++mf) {
#pragma unroll
      for (int r = 0; r < 16; ++r) {
        const int mrow = wm * (BM / WM) + mf * 32 + (r & 3) + 8 * (r >> 2) + 4 * lh;
        const int rr = rb * BM + mrow;
        const int h = rr >> wshift;
        const int w = rr & (W - 1);
        float v = acc[mf][r] + bv;
        if (TAPS == 9) v = fmaxf(v, 0.f);  // relu for tower convs; in_proj is linear
        outp[((long)(img * (H + 2) + h + 1) * (W + 2) + w + 1) * 256 + co] = __float2bfloat16(v);
      }
    }
  } else {
    float lsum = 0.f;
    const bool valid = co < Cout;
    const float bv = valid ? bias[co] : 0.f;
    int aidx = 0, sub = 0;
    if constexpr (EPI == 1) { aidx = co / 80; sub = co - aidx * 80; }
    else { aidx = co >> 2; sub = co & 3; }
    if (valid) {
#pragma unroll
      for (int mf = 0; mf < MF; ++mf) {
#pragma unroll
        for (int r = 0; r < 16; ++r) {
          const int mrow = wm * (BM / WM) + mf * 32 + (r & 3) + 8 * (r >> 2) + 4 * lh;
          const int rr = rb * BM + mrow;
          const int idx = abase + rr * 9 + aidx;
          const int label = labels[(long)img * NT + idx];
          const float z = acc[mf][r] + bv;
          if constexpr (EPI == 1) {
            if (label >= 0) {
              const float tt = (label == sub) ? 1.f : 0.f;
              const float ce = fmaxf(z, 0.f) - z * tt + log1pf(expf(-fabsf(z)));
              const float p = 1.f / (1.f + expf(-z));
              const float pt = p * tt + (1.f - p) * (1.f - tt);
              const float om = 1.f - pt;
              lsum += (0.25f * tt + 0.75f * (1.f - tt)) * ce * om * om;
            }
          } else {
            if (label >= 0 && label != 80) {
              lsum += fabsf(z - tdel[((long)img * NT + idx) * 4 + sub]);
            }
          }
        }
      }
    }
#pragma unroll
    for (int off = 32; off > 0; off >>= 1) lsum += __shfl_down(lsum, off, 64);
    __syncthreads();
    float* red = (float*)smem;
    if (lane == 0) red[wid] = lsum;
    __syncthreads();
    if (tid == 0) {
      float s = 0.f;
      for (int i = 0; i < BLOCK / 64; ++i) s += red[i];
      atomicAdd(lout, s * 0.01f);
    }
  }
}

// ---------------- host ----------------

struct Ctx {
  const bf16 *wip, *wcls, *wbox, *wsc, *wpred;
  const float *ipb, *ccb, *csb, *bcb, *bpb;
  const int* labels;
  const float* tdel;
  bf16 *xb, *t0, *t1;
  float* out;
};

template <int BM, int WM, int WN, int PM>
static void run_level(const Ctx& P, int H, int wshift, int abase, hipStream_t s) {
  const int W = 1 << wshift;
  const int mpb = H * W / BM;
  dim3 blk(WM * WN * 64);
  // in_proj (1x1): t0 -> xb
  conv_t<BM, WM, WN, 1, 0, PM><<<dim3(mpb, 4, 2), blk, 0, s>>>(
      P.t0, P.wip, P.ipb, P.xb, H, wshift, nullptr, nullptr, 0, nullptr, 256);
  bf16* pp[2] = {P.t0, P.t1};
  const bf16* cin = P.xb;
  for (int j = 0; j < 4; ++j) {
    conv_t<BM, WM, WN, 9, 0, PM><<<dim3(mpb, 4, 2), blk, 0, s>>>(
        cin, P.wcls + (long)j * 589824, P.ccb + j * 256, pp[j & 1], H, wshift,
        nullptr, nullptr, 0, nullptr, 256);
    cin = pp[j & 1];
  }
  conv_t<BM, WM, WN, 9, 1, PM><<<dim3(mpb, 12, 2), blk, 0, s>>>(
      cin, P.wsc, P.csb, nullptr, H, wshift, P.labels, nullptr, abase, P.out + 0, 720);
  cin = P.xb;
  for (int j = 0; j < 4; ++j) {
    conv_t<BM, WM, WN, 9, 0, PM><<<dim3(mpb, 4, 2), blk, 0, s>>>(
        cin, P.wbox + (long)j * 589824, P.bcb + j * 256, pp[j & 1], H, wshift,
        nullptr, nullptr, 0, nullptr, 256);
    cin = pp[j & 1];
  }
  conv_t<BM, WM, WN, 9, 2, PM><<<dim3(mpb, 1, 2), blk, 0, s>>>(
      cin, P.wpred, P.bpb, nullptr, H, wshift, P.labels, P.tdel, abase, P.out + 1, 36);
}

static inline int igrid(long n, int cap) {
  long g = (n + 255) / 256;
  return (int)(g > cap ? cap : g);
}

extern "C" void kernel_launch(void* const* d_in, const int* in_sizes, int n_in,
                              void* d_out, int out_size, void* d_ws, size_t ws_size,
                              hipStream_t stream) {
  const float* feat_in[5] = {(const float*)d_in[0], (const float*)d_in[1],
                             (const float*)d_in[2], (const float*)d_in[3],
                             (const float*)d_in[4]};
  const int* labels = (const int*)d_in[5];
  const float* adeltas = (const float*)d_in[6];
  const float* ipw = (const float*)d_in[7];
  const float* ipb = (const float*)d_in[8];
  const float* ccw = (const float*)d_in[9];
  const float* ccb = (const float*)d_in[10];
  const float* csw = (const float*)d_in[11];
  const float* csb = (const float*)d_in[12];
  const float* bcw = (const float*)d_in[13];
  const float* bcb = (const float*)d_in[14];
  const float* bpw = (const float*)d_in[15];
  const float* bpb = (const float*)d_in[16];
  float* out = (float*)d_out;

  const long BUF = 8652800;  // 2*130*130*256
  bf16* ws = (bf16*)d_ws;
  bf16* xb = ws;
  bf16* t0 = ws + BUF;
  bf16* t1 = ws + 2 * BUF;
  bf16* wp_ip = ws + 3 * BUF;                 //   327,680
  bf16* wp_cls = wp_ip + 327680;              // 2,359,296
  bf16* wp_box = wp_cls + 2359296;            // 2,359,296
  bf16* wp_sc = wp_box + 2359296;             // 1,769,472
  bf16* wp_pred = wp_sc + 1769472;            //   147,456

  hipMemsetAsync(d_out, 0, 2 * sizeof(float), stream);

  // weight prep
  prep_w<<<igrid(5L * 8192, 2048), 256, 0, stream>>>(ipw, wp_ip, 256, 4, 1, 5, 65536);
  prep_w<<<igrid(4L * 73728, 2048), 256, 0, stream>>>(ccw, wp_cls, 256, 4, 9, 4, 589824);
  prep_w<<<igrid(4L * 73728, 2048), 256, 0, stream>>>(bcw, wp_box, 256, 4, 9, 4, 589824);
  prep_w<<<igrid(221184L, 2048), 256, 0, stream>>>(csw, wp_sc, 720, 12, 9, 1, 0);
  prep_w<<<igrid(18432L, 2048), 256, 0, stream>>>(bpw, wp_pred, 36, 1, 9, 1, 0);

  static const int LH[5] = {128, 64, 32, 16, 8};
  static const int LS[5] = {7, 6, 5, 4, 3};
  static const int AB[5] = {0, 147456, 184320, 193536, 195840};

  Ctx P;
  P.wcls = wp_cls; P.wbox = wp_box; P.wsc = wp_sc; P.wpred = wp_pred;
  P.ccb = ccb; P.csb = csb; P.bcb = bcb; P.bpb = bpb;
  P.labels = labels; P.tdel = adeltas;
  P.xb = xb; P.t0 = t0; P.t1 = t1; P.out = out;

  for (int l = 0; l < 5; ++l) {
    const int H = LH[l], wsh = LS[l];
    P.wip = wp_ip + (long)l * 65536;
    P.ipb = ipb + l * 256;
    halo3_kernel<<<igrid(3L * 2 * (2 * (H + 2 + H)) * 256, 2048), 256, 0, stream>>>(
        xb, BUF, H, H);
    cast_feat_kernel<<<igrid(2L * H * H * 64, 2048), 256, 0, stream>>>(
        feat_in[l], t0, H, wsh);
    switch (l) {
      case 0: run_level<256, 4, 2, 520>(P, H, wsh, AB[l], stream); break;
      case 1: run_level<128, 2, 2, 264>(P, H, wsh, AB[l], stream); break;
      case 2: run_level<128, 2, 2, 264>(P, H, wsh, AB[l], stream); break;
      case 3: run_level<128, 2, 2, 264>(P, H, wsh, AB[l], stream); break;
      case 4: run_level<64, 2, 2, 100>(P, H, wsh, AB[l], stream); break;
    }
  }
}